// Round 2
// baseline (108.829 us; speedup 1.0000x reference)
//
#include <hip/hip_runtime.h>
#include <hip/hip_bf16.h>

// ---------------------------------------------------------------------------
// Clebsch-Gordan coefficients (L_MAX = 3), computed per-term at compile time.
// Each term is its own small constexpr evaluation (avoids clang's per-
// expression constexpr step limit that killed the single-table approach).
// ---------------------------------------------------------------------------
constexpr int L_MAX = 3;
constexpr int NUM_ORDERS = (L_MAX + 1) * (L_MAX + 1);  // 16

constexpr double cfact(int n) {
    double r = 1.0;
    for (int i = 2; i <= n; ++i) r *= (double)i;
    return r;
}

constexpr double csqrt(double x) {
    if (x <= 0.0) return 0.0;
    double g = x > 1.0 ? x : 1.0;
    for (int i = 0; i < 60; ++i) g = 0.5 * (g + x / g);
    return g;
}

constexpr int cmax2(int a, int b) { return a > b ? a : b; }
constexpr int cmin2(int a, int b) { return a < b ? a : b; }
constexpr int cabs(int a) { return a < 0 ? -a : a; }

constexpr double cg_coeff(int l1, int m1, int l2, int m2, int l, int m) {
    if (m1 + m2 != m) return 0.0;
    double pref = csqrt((double)(2 * l + 1) * cfact(l + l1 - l2) * cfact(l - l1 + l2)
                        * cfact(l1 + l2 - l) / cfact(l1 + l2 + l + 1));
    pref *= csqrt(cfact(l + m) * cfact(l - m) * cfact(l1 - m1)
                  * cfact(l1 + m1) * cfact(l2 - m2) * cfact(l2 + m2));
    int kmin = cmax2(0, cmax2(l2 - l - m1, l1 + m2 - l));
    int kmax = cmin2(l1 + l2 - l, cmin2(l1 - m1, l2 + m2));
    double s = 0.0;
    for (int k = kmin; k <= kmax; ++k) {
        double sign = (k % 2 == 0) ? 1.0 : -1.0;
        s += sign / (cfact(k) * cfact(l1 + l2 - l - k) * cfact(l1 - m1 - k)
                     * cfact(l2 + m2 - k) * cfact(l - l2 + m1 + k)
                     * cfact(l - l1 - m2 + k));
    }
    return pref * s;
}

// --- template-recursive loop nest: emit one fma per nonzero CG term --------

template <int L, int L1, int L2, int M, int M1>
struct TermEmit {
    __device__ static __forceinline__ void run(const float* a, const float* b, float* acc) {
        constexpr int M2 = M - M1;
        constexpr double Vd = (M2 >= -L2 && M2 <= L2)
                                  ? cg_coeff(L1, M1, L2, M2, L, M) : 0.0;
        constexpr float V = (float)Vd;
        if constexpr (V != 0.0f) {
            acc[L * L + L + M] = fmaf(
                V, a[L1 * L1 + L1 + M1] * b[L2 * L2 + L2 + M2],
                acc[L * L + L + M]);
        }
    }
};

template <int L, int L1, int L2, int M, int M1, bool Done = (M1 > L1)>
struct LoopM1 {
    __device__ static __forceinline__ void run(const float* a, const float* b, float* acc) {
        TermEmit<L, L1, L2, M, M1>::run(a, b, acc);
        LoopM1<L, L1, L2, M, M1 + 1>::run(a, b, acc);
    }
};
template <int L, int L1, int L2, int M, int M1>
struct LoopM1<L, L1, L2, M, M1, true> {
    __device__ static __forceinline__ void run(const float*, const float*, float*) {}
};

template <int L, int L1, int L2, int M, bool Done = (M > L)>
struct LoopM {
    __device__ static __forceinline__ void run(const float* a, const float* b, float* acc) {
        LoopM1<L, L1, L2, M, -L1>::run(a, b, acc);
        LoopM<L, L1, L2, M + 1>::run(a, b, acc);
    }
};
template <int L, int L1, int L2, int M>
struct LoopM<L, L1, L2, M, true> {
    __device__ static __forceinline__ void run(const float*, const float*, float*) {}
};

template <int L, int L1, int L2, bool Done = (L2 > cmin2(L_MAX, L + L1))>
struct LoopL2 {
    __device__ static __forceinline__ void run(const float* a, const float* b, float* acc) {
        LoopM<L, L1, L2, -L>::run(a, b, acc);
        LoopL2<L, L1, L2 + 1>::run(a, b, acc);
    }
};
template <int L, int L1, int L2>
struct LoopL2<L, L1, L2, true> {
    __device__ static __forceinline__ void run(const float*, const float*, float*) {}
};

template <int L, int L1, bool Done = (L1 > L_MAX)>
struct LoopL1 {
    __device__ static __forceinline__ void run(const float* a, const float* b, float* acc) {
        LoopL2<L, L1, cabs(L - L1)>::run(a, b, acc);
        LoopL1<L, L1 + 1>::run(a, b, acc);
    }
};
template <int L, int L1>
struct LoopL1<L, L1, true> {
    __device__ static __forceinline__ void run(const float*, const float*, float*) {}
};

template <int L, bool Done = (L > L_MAX)>
struct LoopL {
    __device__ static __forceinline__ void run(const float* a, const float* b, float* acc) {
        LoopL1<L, 0>::run(a, b, acc);
        LoopL<L + 1>::run(a, b, acc);
    }
};
template <int L>
struct LoopL<L, true> {
    __device__ static __forceinline__ void run(const float*, const float*, float*) {}
};

// ---------------------------------------------------------------------------
// One thread per (n, c). c = lane & 63 -> every x1/x2/out access is a fully
// coalesced 256 B wave transaction. 478 nonzero terms fully unrolled with
// literal CG values; zero terms eliminated at compile time.
// ---------------------------------------------------------------------------
__global__ __launch_bounds__(256) void tp_cg_kernel(
        const float* __restrict__ x1, const float* __restrict__ x2,
        float* __restrict__ out, int n_batch) {
    const int tid = blockIdx.x * 256 + threadIdx.x;
    const int c = tid & 63;
    const int n = tid >> 6;
    if (n >= n_batch) return;

    const long base = (long)n * (NUM_ORDERS * 64) + c;
    const float* __restrict__ p1 = x1 + base;
    const float* __restrict__ p2 = x2 + base;

    float a[NUM_ORDERS], b[NUM_ORDERS], acc[NUM_ORDERS];
#pragma unroll
    for (int m = 0; m < NUM_ORDERS; ++m) {
        a[m] = p1[m * 64];
        b[m] = p2[m * 64];
        acc[m] = 0.0f;
    }

    LoopL<0>::run(a, b, acc);

    float* __restrict__ po = out + base;
#pragma unroll
    for (int m = 0; m < NUM_ORDERS; ++m) po[m * 64] = acc[m];
}

extern "C" void kernel_launch(void* const* d_in, const int* in_sizes, int n_in,
                              void* d_out, int out_size, void* d_ws, size_t ws_size,
                              hipStream_t stream) {
    const float* x1 = (const float*)d_in[0];
    const float* x2 = (const float*)d_in[1];
    // d_in[2..5] (CG_vals, M1, M2, Mseg) are compile-time constants -> ignored.
    float* out = (float*)d_out;

    const int n_batch = in_sizes[0] / (NUM_ORDERS * 64);  // 8192
    const int total_threads = n_batch * 64;
    const int block = 256;
    const int grid = (total_threads + block - 1) / block;

    tp_cg_kernel<<<grid, block, 0, stream>>>(x1, x2, out, n_batch);
}